// Round 3
// baseline (1387.156 us; speedup 1.0000x reference)
//
#include <hip/hip_runtime.h>

// GPTQ 4-bit dequant GEMM, two-pass: out[M,N] = x[M,K] @ W[K,N]
// M = 8192, K = 4096, N = 11008, GROUP = 128.
//
// Pass 1: x fp32 -> bf16 (workspace).
// Pass 2: qweight -> W^T [N,K] bf16 (workspace); wave-per-row, lanes cover k
//         -> coalesced 1KB stores (R1 version had 16B scattered stores).
// Pass 3: 256x256 phase-interleaved bf16 GEMM (T1+T2+T3+T4+T5):
//   BK=32, LDS ring of 4 K-tile slots (128 KiB), 8 waves (2Mx4N),
//   per K-tile: 2 phases x 16 MFMA, raw s_barrier (no vmcnt(0) drain),
//   staging leads 3 K-tiles, boundary s_waitcnt vmcnt(8) only.
//   Ring slot (t+3)&3 was last read in window t-1 -> stores never race reads.
//   Swizzle (fixed vs R2): LDS(r,c) holds global chunk c ^ ((r>>1)&3).
//   Bank sets for BK=32 rows are keyed by (r&1, chunk) = 8 slots; h=(r>>1)&3
//   gives each 16-lane ds_read_b128 phase group 8 slots x 2 lanes = conflict-
//   free (the h=r&3 of R2 hit only 4 slots = 4-way conflict).

typedef __bf16 bf16;
typedef __attribute__((ext_vector_type(8))) __bf16 bf16x8;
typedef __attribute__((ext_vector_type(4))) __bf16 bf16x4;
typedef __attribute__((ext_vector_type(4))) float floatx4;

constexpr int KDIM = 4096;
constexpr int NDIM = 11008;
constexpr int GROUP = 128;
constexpr int NT = KDIM / 32;      // 128 K-tiles of BK=32
constexpr int NBX = NDIM / 256;    // 43

// ---------------- pass 1: x fp32 -> bf16 ----------------
__global__ __launch_bounds__(256)
void cvt_x(const float* __restrict__ x, bf16* __restrict__ xb) {
  const int idx = (blockIdx.x * 256 + threadIdx.x) * 8;
  const float4 a = *(const float4*)&x[idx];
  const float4 b = *(const float4*)&x[idx + 4];
  bf16x8 pk = { (bf16)a.x, (bf16)a.y, (bf16)a.z, (bf16)a.w,
                (bf16)b.x, (bf16)b.y, (bf16)b.z, (bf16)b.w };
  *(bf16x8*)&xb[idx] = pk;
}

// ---------------- pass 2: dequant qweight -> W^T [N, K] bf16 ----------------
// One wave per output row n; lane l covers k-words it*64+l -> stores are
// 1KB contiguous per wave-instruction. qweight reads are lane-scattered
// (stride NDIM*4B) but each 64B line is shared by 16 n-rows via L2.
__global__ __launch_bounds__(256)
void dequant_wt(const int* __restrict__ qweight, const int* __restrict__ qzeros,
                const float* __restrict__ scales, bf16* __restrict__ wt) {
  const int n    = (blockIdx.x << 2) | (threadIdx.x >> 6);   // 0..11007
  const int lane = threadIdx.x & 63;
#pragma unroll
  for (int it = 0; it < 8; ++it) {
    const int kw = it * 64 + lane;                 // packed word 0..511
    const int g  = kw >> 4;                        // group (16 words/group)
    const float sc = scales[g * NDIM + n];
    const unsigned zw = (unsigned)qzeros[g * (NDIM / 8) + (n >> 3)];
    const float zs = (float)(((zw >> ((n & 7) * 4)) & 0xF) + 1) * sc;
    const unsigned w = (unsigned)qweight[kw * NDIM + n];
    bf16x8 pk;
#pragma unroll
    for (int j = 0; j < 8; ++j)
      pk[j] = (bf16)((float)((w >> (4 * j)) & 0xF) * sc - zs);  // sc*(q-z)
    *(bf16x8*)&wt[(long)n * KDIM + kw * 8] = pk;
  }
}

// ---------------- pass 3: 256x256 phase-interleaved bf16 GEMM ----------------

#define GWINDOW(T, DO_STAGE, VM)                                               \
  {                                                                            \
    const int slot_ = (T) & 3;                                                 \
    const bf16* __restrict__ Asl = &As[slot_][0];                              \
    const bf16* __restrict__ Bsl = &Bs[slot_][0];                              \
    /* ---- phase A: read A-half0 + all B, stage A-halves of T+3 ---- */       \
    _Pragma("unroll") for (int i = 0; i < 4; ++i)                              \
      af[i] = *(const bf16x8*)&Asl[(arow0 + i * 16) * 32 + csw];               \
    _Pragma("unroll") for (int j = 0; j < 4; ++j)                              \
      bfr[j] = *(const bf16x8*)&Bsl[(brow0 + j * 16) * 32 + csw];              \
    if (DO_STAGE) { STAGE_A((T) + 3, 0); STAGE_A((T) + 3, 1); }                \
    __builtin_amdgcn_s_barrier();                                              \
    __builtin_amdgcn_s_setprio(1);                                             \
    _Pragma("unroll") for (int i = 0; i < 4; ++i)                              \
      _Pragma("unroll") for (int j = 0; j < 4; ++j)                            \
        acc[i][j] = __builtin_amdgcn_mfma_f32_16x16x32_bf16(af[i], bfr[j],     \
                                                            acc[i][j], 0, 0, 0);\
    __builtin_amdgcn_s_setprio(0);                                             \
    __builtin_amdgcn_s_barrier();                                              \
    /* ---- phase B: read A-half1 (B reused), stage B-halves ---- */           \
    _Pragma("unroll") for (int i = 0; i < 4; ++i)                              \
      af[i] = *(const bf16x8*)&Asl[(arow0 + 64 + i * 16) * 32 + csw];          \
    if (DO_STAGE) { STAGE_B((T) + 3, 0); STAGE_B((T) + 3, 1); }                \
    __builtin_amdgcn_s_barrier();                                              \
    __builtin_amdgcn_s_setprio(1);                                             \
    _Pragma("unroll") for (int i = 0; i < 4; ++i)                              \
      _Pragma("unroll") for (int j = 0; j < 4; ++j)                            \
        acc[4 + i][j] = __builtin_amdgcn_mfma_f32_16x16x32_bf16(af[i], bfr[j], \
                                                          acc[4 + i][j], 0, 0, 0);\
    __builtin_amdgcn_s_setprio(0);                                             \
    if ((VM) == 8)      asm volatile("s_waitcnt vmcnt(8)" ::: "memory");       \
    else if ((VM) == 4) asm volatile("s_waitcnt vmcnt(4)" ::: "memory");       \
    else if ((VM) == 0) asm volatile("s_waitcnt vmcnt(0)" ::: "memory");       \
    __builtin_amdgcn_s_barrier();                                              \
  }

#define STAGE_A(T, HALF)                                                       \
  __builtin_amdgcn_global_load_lds(                                            \
      (const __attribute__((address_space(1))) void*)(Ag + (long)(T) * 32 +    \
                                                      (long)(HALF) * 128 * KDIM),\
      (__attribute__((address_space(3))) void*)&As[(T) & 3][(HALF) * 4096 +    \
                                                            wave * 512],       \
      16, 0, 0)
#define STAGE_B(T, HALF)                                                       \
  __builtin_amdgcn_global_load_lds(                                            \
      (const __attribute__((address_space(1))) void*)(Bg + (long)(T) * 32 +    \
                                                      (long)(HALF) * 128 * KDIM),\
      (__attribute__((address_space(3))) void*)&Bs[(T) & 3][(HALF) * 4096 +    \
                                                            wave * 512],       \
      16, 0, 0)

__global__ __launch_bounds__(512, 2)
void gemm_bf16(const bf16* __restrict__ A, const bf16* __restrict__ BT,
               float* __restrict__ out) {
  __shared__ bf16 As[4][256 * 32];   // 64 KiB: ring of 4 A K-tiles
  __shared__ bf16 Bs[4][256 * 32];   // 64 KiB: ring of 4 B K-tiles

  const int tid  = threadIdx.x;
  const int lane = tid & 63;
  const int wave = tid >> 6;        // 0..7
  const int quad = lane >> 4;
  const int l16  = lane & 15;
  const int wr   = wave >> 2;       // 0..1: m-half
  const int wc   = wave & 3;        // 0..3: n-quarter

  // T1: XCD-aware block swizzle (nwg = 1376, % 8 == 0 -> simple bijection)
  const int nwg  = gridDim.x * gridDim.y;
  const int orig = blockIdx.y * gridDim.x + blockIdx.x;
  const int wg   = ((nwg & 7) == 0) ? (orig & 7) * (nwg >> 3) + (orig >> 3) : orig;
  const int bx   = wg % NBX;
  const int by   = wg / NBX;
  const int row0 = by * 256;
  const int col0 = bx * 256;

  // staging: wave w covers rows w*16..+16 of each 128-row half-tile.
  // linear LDS dest (base + lane*16B) => LDS row = w*16 + (lane>>2),
  // chunk = lane&3. Source fetches chunk (lane&3) ^ h(row), h(r) = (r>>1)&3,
  // so LDS(r,c) holds global chunk c ^ ((r>>1)&3).
  const int srow = lane >> 2;
  const int sch  = (lane & 3) ^ ((lane >> 3) & 3);
  const bf16* Ag = A  + (long)(row0 + wave * 16 + srow) * KDIM + sch * 8;
  const bf16* Bg = BT + (long)(col0 + wave * 16 + srow) * KDIM + sch * 8;

  // frag reads: row r = ... + l16 (r>>1)&3 == (l16>>1)&3 for all frag rows
  const int csw   = (quad ^ ((l16 >> 1) & 3)) << 3;  // 16B chunk, elem offset
  const int arow0 = wr * 128 + l16;
  const int brow0 = wc * 64 + l16;

  floatx4 acc[8][4];
#pragma unroll
  for (int i = 0; i < 8; ++i)
#pragma unroll
    for (int j = 0; j < 4; ++j) acc[i][j] = (floatx4)0.f;

  bf16x8 af[4], bfr[4];

  // prologue: stage tiles 0,1,2 (12 loads/wave); vmcnt(8) retires tile 0
#pragma unroll
  for (int t = 0; t < 3; ++t) {
    STAGE_A(t, 0); STAGE_A(t, 1); STAGE_B(t, 0); STAGE_B(t, 1);
  }
  asm volatile("s_waitcnt vmcnt(8)" ::: "memory");
  __builtin_amdgcn_s_barrier();

  // steady state: window t reads tile t, stages t+3 into slot (t+3)&3
  // (last read in window t-1); boundary vmcnt(8) retires tile t+1's loads.
  int t = 0;
  for (; t < NT - 3; ++t) GWINDOW(t, true, 8);
  GWINDOW(t, false, 4); ++t;
  GWINDOW(t, false, 0); ++t;
  GWINDOW(t, false, -1);

  // epilogue: C/D layout col=lane&15, row=quad*4+reg (m89-verified)
#pragma unroll
  for (int mf = 0; mf < 8; ++mf) {
#pragma unroll
    for (int j = 0; j < 4; ++j) {
      const int r0 = row0 + wr * 128 + mf * 16 + quad * 4;
      const int c  = col0 + wc * 64 + j * 16 + l16;
#pragma unroll
      for (int r = 0; r < 4; ++r)
        out[(long)(r0 + r) * NDIM + c] = acc[mf][j][r];
    }
  }
}

// ---------------- fallback: fused kernel (used only if ws too small) ----------------
__global__ __launch_bounds__(256)
void gptq_gemm(const float* __restrict__ x, const int* __restrict__ qweight,
               const int* __restrict__ qzeros, const float* __restrict__ scales,
               float* __restrict__ out) {
  constexpr int BM = 128, BN = 128, FBK = 32, LDT = 40;
  __shared__ bf16 Asf[BM * LDT];
  __shared__ bf16 Bsf[BN * LDT];

  const int tid  = threadIdx.x;
  const int lane = tid & 63;
  const int wave = tid >> 6;
  const int quad = lane >> 4;
  const int l16  = lane & 15;
  const int wm   = (wave >> 1) * 64;
  const int wn   = (wave & 1) * 64;

  const int row0 = blockIdx.y * BM;
  const int col0 = blockIdx.x * BN;

  const int nb   = tid & 127;
  const int kpl0 = tid >> 7;
  const int gn   = col0 + nb;

  floatx4 acc[4][4];
#pragma unroll
  for (int i = 0; i < 4; ++i)
#pragma unroll
    for (int j = 0; j < 4; ++j) acc[i][j] = (floatx4)0.f;

  for (int g = 0; g < KDIM / GROUP; ++g) {
    const float sc = scales[g * NDIM + gn];
    const unsigned int zw = (unsigned int)qzeros[g * (NDIM / 8) + (gn >> 3)];
    const float zs = (float)((int)((zw >> ((gn & 7) * 4)) & 0xF) + 1) * sc;

    for (int kk = 0; kk < GROUP / FBK; ++kk) {
      const int k0 = g * GROUP + kk * FBK;
#pragma unroll
      for (int r = 0; r < 4; ++r) {
        const int flat = r * 256 + tid;
        const int m  = flat >> 3;
        const int k4 = (flat & 7) << 2;
        const float4 v = *(const float4*)&x[(row0 + m) * KDIM + k0 + k4];
        bf16x4 pk = { (bf16)v.x, (bf16)v.y, (bf16)v.z, (bf16)v.w };
        *(bf16x4*)&Asf[m * LDT + k4] = pk;
      }
      const int kp0 = k0 >> 3;
#pragma unroll
      for (int w = 0; w < 2; ++w) {
        const int kpl = kpl0 + w * 2;
        const unsigned int word = (unsigned int)qweight[(kp0 + kpl) * NDIM + gn];
        bf16x8 pk;
#pragma unroll
        for (int j = 0; j < 8; ++j) {
          const float q = (float)((word >> (4 * j)) & 0xF);
          pk[j] = (bf16)(q * sc - zs);
        }
        const int sw = kpl ^ ((nb >> 3) & 3);
        *(bf16x8*)&Bsf[nb * LDT + sw * 8] = pk;
      }
      __syncthreads();
      bf16x8 af[4], bfr[4];
#pragma unroll
      for (int i = 0; i < 4; ++i)
        af[i] = *(bf16x8*)&Asf[(wm + i * 16 + l16) * LDT + quad * 8];
#pragma unroll
      for (int j = 0; j < 4; ++j) {
        const int nr = wn + j * 16 + l16;
        const int sw = quad ^ ((nr >> 3) & 3);
        bfr[j] = *(bf16x8*)&Bsf[nr * LDT + sw * 8];
      }
#pragma unroll
      for (int i = 0; i < 4; ++i)
#pragma unroll
        for (int j = 0; j < 4; ++j)
          acc[i][j] = __builtin_amdgcn_mfma_f32_16x16x32_bf16(af[i], bfr[j], acc[i][j], 0, 0, 0);
      __syncthreads();
    }
  }
#pragma unroll
  for (int i = 0; i < 4; ++i) {
#pragma unroll
    for (int j = 0; j < 4; ++j) {
      const int r0 = row0 + wm + i * 16 + quad * 4;
      const int c  = col0 + wn + j * 16 + l16;
#pragma unroll
      for (int r = 0; r < 4; ++r)
        out[(r0 + r) * NDIM + c] = acc[i][j][r];
    }
  }
}

extern "C" void kernel_launch(void* const* d_in, const int* in_sizes, int n_in,
                              void* d_out, int out_size, void* d_ws, size_t ws_size,
                              hipStream_t stream) {
  const float* x       = (const float*)d_in[0];
  const int*   qweight = (const int*)d_in[1];
  const int*   qzeros  = (const int*)d_in[2];
  const float* scales  = (const float*)d_in[3];
  float*       out     = (float*)d_out;

  const int M = in_sizes[0] / KDIM;          // 8192

  const size_t xb_bytes = (size_t)M * KDIM * sizeof(bf16);
  const size_t wt_bytes = (size_t)NDIM * KDIM * sizeof(bf16);

  if (d_ws && ws_size >= xb_bytes + wt_bytes && (M % 256) == 0 &&
      ((M * KDIM) % (8 * 256)) == 0) {
    bf16* xb = (bf16*)d_ws;
    bf16* wt = (bf16*)((char*)d_ws + xb_bytes);
    cvt_x<<<(M * KDIM) / (8 * 256), 256, 0, stream>>>(x, xb);
    dequant_wt<<<NDIM / 4, 256, 0, stream>>>(qweight, qzeros, scales, wt);
    gemm_bf16<<<dim3(NDIM / 256, M / 256), 512, 0, stream>>>(xb, wt, out);
  } else {
    gptq_gemm<<<dim3(NDIM / 128, M / 128), 256, 0, stream>>>(x, qweight, qzeros, scales, out);
  }
}